// Round 5
// baseline (352.004 us; speedup 1.0000x reference)
//
#include <hip/hip_runtime.h>
#include <hip/hip_bf16.h>

#define D 128

typedef __bf16 bf16x8 __attribute__((ext_vector_type(8)));
typedef unsigned short u16x8 __attribute__((ext_vector_type(8)));
typedef float f32x4 __attribute__((ext_vector_type(4)));

__device__ __forceinline__ unsigned short f2bf(float f) {
    unsigned u = __float_as_uint(f);
    u += 0x7FFFu + ((u >> 16) & 1u);
    return (unsigned short)(u >> 16);
}
__device__ __forceinline__ float bf2f(unsigned u16) {
    return __uint_as_float(u16 << 16);
}

// WTs[c][k] = [W_nbrs | W_self][k][c] as bf16 (plain transpose, no swizzle:
// B fragments are read through L1/L2, banks don't apply). Also zeroes cnt.
__global__ void k_build_wt(const float* __restrict__ Wn, const float* __restrict__ Ws,
                           unsigned short* __restrict__ WTs,
                           int* __restrict__ cnt, int N) {
    int g = blockIdx.x * blockDim.x + threadIdx.x;   // 0..32767
    int c = g >> 7;          // 0..255
    int k = g & 127;         // 0..127
    float v = (c < 128) ? Wn[k * 128 + c] : Ws[k * 128 + (c - 128)];
    WTs[c * 128 + k] = f2bf(v);
    for (int i = g; i < N; i += 32768) cnt[i] = 0;
}

// Fused 1:1: even blocks = barrier-free zero-LDS GEMM tile (64 rows);
// odd blocks = rank pass (1024 edges, 4 independent atomic chains/thread).
// B fragments are read directly from global (64 KB table, L1/L2-resident).
// Phase 0: y' (bf16, nt-major permuted) ; phase 1: self+bias (f32, same
// permutation) straight into d_out — k_agg unpermutes when it writes.
__global__ __launch_bounds__(256) void k_gemm_rank(
    const float* __restrict__ x, const unsigned short* __restrict__ WTs,
    const float* __restrict__ bias, int N,
    unsigned short* __restrict__ y, float* __restrict__ out,
    const int* __restrict__ edst, int E,
    int* __restrict__ cnt, int* __restrict__ rank) {
    int b = blockIdx.x;
    int tid = threadIdx.x;
    if (b & 1) {
        // ---- rank path ----
        int e0 = (b >> 1) * 1024 + tid;
        #pragma unroll
        for (int k = 0; k < 4; ++k) {
            int e = e0 + k * 256;
            if (e < E) rank[e] = atomicAdd(&cnt[edst[e]], 1);
        }
        return;
    }
    // ---- GEMM path (no LDS, no barriers) ----
    int gb = b >> 1;
    int brow = gb * 64;
    if (brow >= N) return;                   // block-uniform
    int w = tid >> 6, l = tid & 63;
    int row0 = brow + w * 16;
    int c15 = l & 15;
    int kgrp = l >> 4;                       // 0..3
    int arow = row0 + c15;                   // A: row = lane%16
    bool avalid = (arow < N);
    const float* xr = x + (size_t)arow * D;
    bf16x8 afrag[4];
    #pragma unroll
    for (int ks = 0; ks < 4; ++ks) {
        int k0 = ks * 32 + kgrp * 8;         // A: k = 8*(lane/16) + j
        float4 a0, a1;
        if (avalid) { a0 = *(const float4*)(xr + k0); a1 = *(const float4*)(xr + k0 + 4); }
        else { a0 = make_float4(0.f, 0.f, 0.f, 0.f); a1 = a0; }
        bf16x8 f;
        f[0] = (__bf16)a0.x; f[1] = (__bf16)a0.y; f[2] = (__bf16)a0.z; f[3] = (__bf16)a0.w;
        f[4] = (__bf16)a1.x; f[5] = (__bf16)a1.y; f[6] = (__bf16)a1.z; f[7] = (__bf16)a1.w;
        afrag[ks] = f;
    }
    int orow = row0 + kgrp * 4;              // C/D: row = 4*(lane/16) + j
    const unsigned short* Bbase = WTs + (size_t)c15 * 128 + kgrp * 8;
    f32x4 acc[8];
    #pragma unroll
    for (int nt = 0; nt < 8; ++nt) {         // phase 0: y = bf16(x@W_nbrs)
        f32x4 a = {0.f, 0.f, 0.f, 0.f};
        #pragma unroll
        for (int ks = 0; ks < 4; ++ks) {
            const bf16x8* bp = (const bf16x8*)(Bbase + nt * 16 * 128 + ks * 32);
            a = __builtin_amdgcn_mfma_f32_16x16x32_bf16(afrag[ks], *bp, a, 0, 0, 0);
        }
        acc[nt] = a;
    }
    // permuted y store: y'[r][c15*8+nt] = C[r][nt*16+c15]; 16 B per (thread,row)
    #pragma unroll
    for (int j = 0; j < 4; ++j) {
        int r = orow + j;
        if (r < N) {
            u16x8 f;
            #pragma unroll
            for (int nt = 0; nt < 8; ++nt) f[nt] = f2bf(acc[nt][j]);
            *(u16x8*)(y + (size_t)r * D + c15 * 8) = f;
        }
    }
    #pragma unroll
    for (int nt = 0; nt < 8; ++nt) {         // phase 1: x@W_self
        f32x4 a = {0.f, 0.f, 0.f, 0.f};
        #pragma unroll
        for (int ks = 0; ks < 4; ++ks) {
            const bf16x8* bp = (const bf16x8*)(Bbase + (128 + nt * 16) * 128 + ks * 32);
            a = __builtin_amdgcn_mfma_f32_16x16x32_bf16(afrag[ks], *bp, a, 0, 0, 0);
        }
        acc[nt] = a;
    }
    float bv[8];
    #pragma unroll
    for (int nt = 0; nt < 8; ++nt) bv[nt] = bias[nt * 16 + c15];
    // permuted f32 store of self+bias into out; k_agg unpermutes later.
    #pragma unroll
    for (int j = 0; j < 4; ++j) {
        int r = orow + j;
        if (r < N) {
            float4 s0 = make_float4(acc[0][j] + bv[0], acc[1][j] + bv[1],
                                    acc[2][j] + bv[2], acc[3][j] + bv[3]);
            float4 s1 = make_float4(acc[4][j] + bv[4], acc[5][j] + bv[5],
                                    acc[6][j] + bv[6], acc[7][j] + bv[7]);
            float4* op = (float4*)(out + (size_t)r * D + c15 * 8);
            op[0] = s0; op[1] = s1;
        }
    }
}

__global__ void k_scanA(const int* __restrict__ cnt, int N,
                        int* __restrict__ ofs, int* __restrict__ bsum) {
    __shared__ int lds[1024];
    int t = threadIdx.x, i = blockIdx.x * 1024 + t;
    int v = (i < N) ? cnt[i] : 0;
    lds[t] = v; __syncthreads();
    for (int d = 1; d < 1024; d <<= 1) {
        int x = (t >= d) ? lds[t - d] : 0; __syncthreads();
        lds[t] += x; __syncthreads();
    }
    if (i < N) ofs[i] = lds[t] - v;           // local (within-block) exclusive scan
    if (t == 1023) bsum[blockIdx.x] = lds[t]; // block total
}

__global__ void k_scanB(int* __restrict__ bsum, int NB) {   // NB <= 128
    __shared__ int lds[128];
    int t = threadIdx.x;
    int v = (t < NB) ? bsum[t] : 0;
    lds[t] = v; __syncthreads();
    for (int d = 1; d < 128; d <<= 1) {
        int x = (t >= d) ? lds[t - d] : 0; __syncthreads();
        lds[t] += x; __syncthreads();
    }
    if (t < NB) bsum[t] = lds[t] - v;         // exclusive block bases
}

// No atomics: pos = ofs[d] + bsum[d>>10] + rank[e]; pure scatter of uint2.
// 4 edges/thread for scatter MLP.
__global__ __launch_bounds__(256) void k_fill(
    const int* __restrict__ src, const int* __restrict__ dst,
    const float* __restrict__ w, const int* __restrict__ rank, int E,
    const int* __restrict__ ofs, const int* __restrict__ bsum,
    uint2* __restrict__ sorted) {
    int e0 = blockIdx.x * 1024 + threadIdx.x;
    #pragma unroll
    for (int k = 0; k < 4; ++k) {
        int e = e0 + k * 256;
        if (e < E) {
            int d = dst[e];
            int pos = ofs[d] + bsum[d >> 10] + rank[e];
            sorted[pos] = make_uint2((unsigned)src[e], __float_as_uint(w[e]));
        }
    }
}

// One wave per destination node, 4 x 16-lane groups, 8 gathers in flight.
// y is nt-major permuted: y'[r][li*8+m] = C[r][m*16+li] -> lane li's a_m is
// out column li+16m. out currently holds the PERMUTED f32 self+bias (written
// by k_gemm_rank); load it early (latency hidden under the gather loop),
// add, and write the row back unpermuted. Reads complete before stores issue
// (store data depends on loads), and each row is owned by exactly one wave.
__global__ __launch_bounds__(256) void k_agg(
    const unsigned short* __restrict__ y, const uint2* __restrict__ sorted,
    const int* __restrict__ ofs, const int* __restrict__ bsum,
    const int* __restrict__ cnt, int N,
    float* __restrict__ out) {
    int w = threadIdx.x >> 6, l = threadIdx.x & 63;
    int node = blockIdx.x * 4 + w;
    if (node >= N) return;
    int s = ofs[node] + bsum[node >> 10], n = cnt[node];
    int g = l >> 4, li = l & 15;
    float4 s0, s1;
    if (l < 16) {   // early self-load (permuted): self for cols li+16m
        const float4* spf = (const float4*)(out + (size_t)node * D + li * 8);
        s0 = spf[0]; s1 = spf[1];
    }
    const uint2* sp = sorted + s;
    float a0 = 0.f, a1 = 0.f, a2 = 0.f, a3 = 0.f;
    float a4 = 0.f, a5 = 0.f, a6 = 0.f, a7 = 0.f;
    int j = g;
    for (; j + 4 < n; j += 8) {
        uint2 pa = sp[j];
        uint2 pb = sp[j + 4];
        uint4 va = *(const uint4*)(y + (size_t)pa.x * D + li * 8);
        uint4 vb = *(const uint4*)(y + (size_t)pb.x * D + li * 8);
        float wa = __uint_as_float(pa.y), wb = __uint_as_float(pb.y);
        a0 += wa * bf2f(va.x & 0xFFFFu); a1 += wa * bf2f(va.x >> 16);
        a2 += wa * bf2f(va.y & 0xFFFFu); a3 += wa * bf2f(va.y >> 16);
        a4 += wa * bf2f(va.z & 0xFFFFu); a5 += wa * bf2f(va.z >> 16);
        a6 += wa * bf2f(va.w & 0xFFFFu); a7 += wa * bf2f(va.w >> 16);
        a0 += wb * bf2f(vb.x & 0xFFFFu); a1 += wb * bf2f(vb.x >> 16);
        a2 += wb * bf2f(vb.y & 0xFFFFu); a3 += wb * bf2f(vb.y >> 16);
        a4 += wb * bf2f(vb.z & 0xFFFFu); a5 += wb * bf2f(vb.z >> 16);
        a6 += wb * bf2f(vb.w & 0xFFFFu); a7 += wb * bf2f(vb.w >> 16);
    }
    if (j < n) {
        uint2 p = sp[j];
        uint4 v = *(const uint4*)(y + (size_t)p.x * D + li * 8);
        float wt = __uint_as_float(p.y);
        a0 += wt * bf2f(v.x & 0xFFFFu); a1 += wt * bf2f(v.x >> 16);
        a2 += wt * bf2f(v.y & 0xFFFFu); a3 += wt * bf2f(v.y >> 16);
        a4 += wt * bf2f(v.z & 0xFFFFu); a5 += wt * bf2f(v.z >> 16);
        a6 += wt * bf2f(v.w & 0xFFFFu); a7 += wt * bf2f(v.w >> 16);
    }
    // butterfly across the 4 groups (xor 16, then xor 32): all lanes -> full sums
    a0 += __shfl_xor(a0, 16, 64); a1 += __shfl_xor(a1, 16, 64);
    a2 += __shfl_xor(a2, 16, 64); a3 += __shfl_xor(a3, 16, 64);
    a4 += __shfl_xor(a4, 16, 64); a5 += __shfl_xor(a5, 16, 64);
    a6 += __shfl_xor(a6, 16, 64); a7 += __shfl_xor(a7, 16, 64);
    a0 += __shfl_xor(a0, 32, 64); a1 += __shfl_xor(a1, 32, 64);
    a2 += __shfl_xor(a2, 32, 64); a3 += __shfl_xor(a3, 32, 64);
    a4 += __shfl_xor(a4, 32, 64); a5 += __shfl_xor(a5, 32, 64);
    a6 += __shfl_xor(a6, 32, 64); a7 += __shfl_xor(a7, 32, 64);
    if (l < 16) {   // lane li owns cols li+16m; each m-group is one 64-B line
        float* op = out + (size_t)node * D + li;
        op[0]   = a0 + s0.x; op[16]  = a1 + s0.y;
        op[32]  = a2 + s0.z; op[48]  = a3 + s0.w;
        op[64]  = a4 + s1.x; op[80]  = a5 + s1.y;
        op[96]  = a6 + s1.z; op[112] = a7 + s1.w;
    }
}

extern "C" void kernel_launch(void* const* d_in, const int* in_sizes, int n_in,
                              void* d_out, int out_size, void* d_ws, size_t ws_size,
                              hipStream_t stream) {
    const float* x    = (const float*)d_in[0];
    const int*   esrc = (const int*)d_in[1];
    const int*   edst = (const int*)d_in[2];
    const float* ew   = (const float*)d_in[3];
    const float* Wn   = (const float*)d_in[4];
    const float* Wsf  = (const float*)d_in[5];
    const float* bias = (const float*)d_in[6];
    float* out = (float*)d_out;
    int N = in_sizes[0] / D;
    int E = in_sizes[1];

    char* ws = (char*)d_ws;
    size_t off = 0;
    unsigned short* WTs = (unsigned short*)(ws + off); off += 256 * 128 * sizeof(unsigned short);
    unsigned short* yb  = (unsigned short*)(ws + off); off += (size_t)N * D * sizeof(unsigned short);
    off = (off + 255) & ~(size_t)255;
    int* cnt  = (int*)(ws + off); off += (size_t)N * 4; off = (off + 255) & ~(size_t)255;
    int* ofs  = (int*)(ws + off); off += (size_t)N * 4; off = (off + 255) & ~(size_t)255;
    int* bsum = (int*)(ws + off); off += 1024;
    int* rank = (int*)(ws + off); off += (size_t)E * 4; off = (off + 255) & ~(size_t)255;
    uint2* sorted = (uint2*)(ws + off); off += (size_t)E * 8;

    k_build_wt<<<128, 256, 0, stream>>>(Wn, Wsf, WTs, cnt, N);

    int GB = (N + 63) / 64;
    int RB = (E + 1023) / 1024;
    int G2 = (GB > RB ? GB : RB) * 2;
    k_gemm_rank<<<G2, 256, 0, stream>>>(x, WTs, bias, N, yb, out,
                                        edst, E, cnt, rank);

    int NB = (N + 1023) / 1024;
    k_scanA<<<NB, 1024, 0, stream>>>(cnt, N, ofs, bsum);
    k_scanB<<<1, 128, 0, stream>>>(bsum, NB);
    k_fill<<<(E + 1023) / 1024, 256, 0, stream>>>(esrc, edst, ew, rank, E, ofs, bsum, sorted);

    k_agg<<<(N + 3) / 4, 256, 0, stream>>>(yb, sorted, ofs, bsum, cnt, N, out);
}

// Round 6
// 300.609 us; speedup vs baseline: 1.1710x; 1.1710x over previous
//
#include <hip/hip_runtime.h>
#include <hip/hip_bf16.h>

#define D 128

typedef __bf16 bf16x8 __attribute__((ext_vector_type(8)));
typedef unsigned short u16x8 __attribute__((ext_vector_type(8)));
typedef float f32x4 __attribute__((ext_vector_type(4)));

__device__ __forceinline__ unsigned short f2bf(float f) {
    unsigned u = __float_as_uint(f);
    u += 0x7FFFu + ((u >> 16) & 1u);
    return (unsigned short)(u >> 16);
}
__device__ __forceinline__ float bf2f(unsigned u16) {
    return __uint_as_float(u16 << 16);
}

// Build W = [W_nbrs | W_self]^T as bf16, XOR-swizzled so GEMM can stage it
// linearly into LDS and read B fragments conflict-free (rounds 1-3: 0 conflicts).
// Element (k, c) -> WTs[c*128 + (((k>>3) ^ (c&15)) << 3) + (k&7)]
// Also zeroes cnt[] (replaces a separate memset dispatch).
__global__ void k_build_wt(const float* __restrict__ Wn, const float* __restrict__ Ws,
                           unsigned short* __restrict__ WTs,
                           int* __restrict__ cnt, int N) {
    int g = blockIdx.x * blockDim.x + threadIdx.x;   // 0..32767
    int k = g >> 8;          // 0..127
    int c = g & 255;         // 0..255 (coalesced reads along c)
    float v = (c < 128) ? Wn[k * 128 + c] : Ws[k * 128 + (c - 128)];
    int chunk = k >> 3;
    WTs[c * 128 + (((chunk ^ (c & 15)) << 3) | (k & 7))] = f2bf(v);
    for (int i = g; i < N; i += 32768) cnt[i] = 0;
}

// Fused 1:2 (GEMM : rank): b%3==0 -> GEMM tile of 128 rows (each wave owns
// 2 x 16-row tiles); else rank pass (1024 edges, 4 independent atomic chains).
// B staged in LDS (32 KB half at a time, XOR-swizzled reads). 3 barriers per
// 128 rows. Phase 0 -> y' (bf16, nt-major permuted, 16-B stores); phase 1 ->
// self+bias (f32, SAME permutation) straight into d_out; k_agg unpermutes.
__global__ __launch_bounds__(256) void k_gemm_rank(
    const float* __restrict__ x, const unsigned short* __restrict__ WTs,
    const float* __restrict__ bias, int N,
    unsigned short* __restrict__ y, float* __restrict__ out,
    const int* __restrict__ edst, int E,
    int* __restrict__ cnt, int* __restrict__ rank) {
    __shared__ unsigned short sm[128 * 128];   // 32 KB
    int b = blockIdx.x;
    int tid = threadIdx.x;
    if (b % 3 != 0) {
        // ---- rank path (no barriers; block-uniform branch) ----
        int rb = (b / 3) * 2 + (b % 3) - 1;
        int e0 = rb * 1024 + tid;
        #pragma unroll
        for (int k = 0; k < 4; ++k) {
            int e = e0 + k * 256;
            if (e < E) rank[e] = atomicAdd(&cnt[edst[e]], 1);
        }
        return;
    }
    // ---- GEMM path ----
    int gb = b / 3;
    int brow = gb * 128;
    if (brow >= N) return;                   // block-uniform
    int w = tid >> 6, l = tid & 63;
    int row0 = brow + w * 32;                // wave owns rows [row0, row0+32)
    int c15 = l & 15;
    int kgrp = l >> 4;                       // 0..3
    const uint4* gs = (const uint4*)WTs;
    uint4* ss = (uint4*)sm;
    // issue B0 stage loads first (overlap with x loads below)
    uint4 st[8];
    #pragma unroll
    for (int r = 0; r < 8; ++r) st[r] = gs[r * 256 + tid];
    // load A fragments for both row-tiles (16 float4 loads in flight)
    bf16x8 afrag[2][4];
    #pragma unroll
    for (int rt = 0; rt < 2; ++rt) {
        int arow = row0 + rt * 16 + c15;     // A: row = lane%16
        bool avalid = (arow < N);
        const float* xr = x + (size_t)arow * D;
        #pragma unroll
        for (int ks = 0; ks < 4; ++ks) {
            int k0 = ks * 32 + kgrp * 8;     // A: k = 8*(lane/16) + j
            float4 a0, a1;
            if (avalid) { a0 = *(const float4*)(xr + k0); a1 = *(const float4*)(xr + k0 + 4); }
            else { a0 = make_float4(0.f, 0.f, 0.f, 0.f); a1 = a0; }
            bf16x8 f;
            f[0] = (__bf16)a0.x; f[1] = (__bf16)a0.y; f[2] = (__bf16)a0.z; f[3] = (__bf16)a0.w;
            f[4] = (__bf16)a1.x; f[5] = (__bf16)a1.y; f[6] = (__bf16)a1.z; f[7] = (__bf16)a1.w;
            afrag[rt][ks] = f;
        }
    }
    #pragma unroll
    for (int r = 0; r < 8; ++r) ss[r * 256 + tid] = st[r];
    __syncthreads();
    // ---- phase 0: y = bf16(x @ W_nbrs), permuted store ----
    #pragma unroll
    for (int rt = 0; rt < 2; ++rt) {
        f32x4 acc[8];
        #pragma unroll
        for (int nt = 0; nt < 8; ++nt) {
            int c = nt * 16 + c15;
            f32x4 a = {0.f, 0.f, 0.f, 0.f};
            #pragma unroll
            for (int ks = 0; ks < 4; ++ks) {
                int chunk = ks * 4 + kgrp;
                const bf16x8* bp = (const bf16x8*)(sm + c * 128 + ((chunk ^ c15) << 3));
                a = __builtin_amdgcn_mfma_f32_16x16x32_bf16(afrag[rt][ks], *bp, a, 0, 0, 0);
            }
            acc[nt] = a;
        }
        int orow = row0 + rt * 16 + kgrp * 4;  // C/D: row = 4*(lane/16) + j
        #pragma unroll
        for (int j = 0; j < 4; ++j) {
            int r = orow + j;
            if (r < N) {
                u16x8 f;
                #pragma unroll
                for (int nt = 0; nt < 8; ++nt) f[nt] = f2bf(acc[nt][j]);
                *(u16x8*)(y + (size_t)r * D + c15 * 8) = f;
            }
        }
    }
    __syncthreads();                          // all waves done reading B0
    #pragma unroll
    for (int r = 0; r < 8; ++r) st[r] = gs[2048 + r * 256 + tid];
    #pragma unroll
    for (int r = 0; r < 8; ++r) ss[r * 256 + tid] = st[r];
    __syncthreads();
    // ---- phase 1: self+bias (f32), permuted store into d_out ----
    float bv[8];
    #pragma unroll
    for (int nt = 0; nt < 8; ++nt) bv[nt] = bias[nt * 16 + c15];
    #pragma unroll
    for (int rt = 0; rt < 2; ++rt) {
        f32x4 acc[8];
        #pragma unroll
        for (int nt = 0; nt < 8; ++nt) {
            int c = nt * 16 + c15;
            f32x4 a = {0.f, 0.f, 0.f, 0.f};
            #pragma unroll
            for (int ks = 0; ks < 4; ++ks) {
                int chunk = ks * 4 + kgrp;
                const bf16x8* bp = (const bf16x8*)(sm + c * 128 + ((chunk ^ c15) << 3));
                a = __builtin_amdgcn_mfma_f32_16x16x32_bf16(afrag[rt][ks], *bp, a, 0, 0, 0);
            }
            acc[nt] = a;
        }
        int orow = row0 + rt * 16 + kgrp * 4;
        #pragma unroll
        for (int j = 0; j < 4; ++j) {
            int r = orow + j;
            if (r < N) {
                float4 s0 = make_float4(acc[0][j] + bv[0], acc[1][j] + bv[1],
                                        acc[2][j] + bv[2], acc[3][j] + bv[3]);
                float4 s1 = make_float4(acc[4][j] + bv[4], acc[5][j] + bv[5],
                                        acc[6][j] + bv[6], acc[7][j] + bv[7]);
                float4* op = (float4*)(out + (size_t)r * D + c15 * 8);
                op[0] = s0; op[1] = s1;
            }
        }
    }
}

__global__ void k_scanA(const int* __restrict__ cnt, int N,
                        int* __restrict__ ofs, int* __restrict__ bsum) {
    __shared__ int lds[1024];
    int t = threadIdx.x, i = blockIdx.x * 1024 + t;
    int v = (i < N) ? cnt[i] : 0;
    lds[t] = v; __syncthreads();
    for (int d = 1; d < 1024; d <<= 1) {
        int x = (t >= d) ? lds[t - d] : 0; __syncthreads();
        lds[t] += x; __syncthreads();
    }
    if (i < N) ofs[i] = lds[t] - v;           // local (within-block) exclusive scan
    if (t == 1023) bsum[blockIdx.x] = lds[t]; // block total
}

__global__ void k_scanB(int* __restrict__ bsum, int NB) {   // NB <= 128
    __shared__ int lds[128];
    int t = threadIdx.x;
    int v = (t < NB) ? bsum[t] : 0;
    lds[t] = v; __syncthreads();
    for (int d = 1; d < 128; d <<= 1) {
        int x = (t >= d) ? lds[t - d] : 0; __syncthreads();
        lds[t] += x; __syncthreads();
    }
    if (t < NB) bsum[t] = lds[t] - v;         // exclusive block bases
}

// No atomics: pos = ofs[d] + bsum[d>>10] + rank[e]; pure scatter of uint2.
// 4 edges/thread for scatter MLP.
__global__ __launch_bounds__(256) void k_fill(
    const int* __restrict__ src, const int* __restrict__ dst,
    const float* __restrict__ w, const int* __restrict__ rank, int E,
    const int* __restrict__ ofs, const int* __restrict__ bsum,
    uint2* __restrict__ sorted) {
    int e0 = blockIdx.x * 1024 + threadIdx.x;
    #pragma unroll
    for (int k = 0; k < 4; ++k) {
        int e = e0 + k * 256;
        if (e < E) {
            int d = dst[e];
            int pos = ofs[d] + bsum[d >> 10] + rank[e];
            sorted[pos] = make_uint2((unsigned)src[e], __float_as_uint(w[e]));
        }
    }
}

// One wave per destination node, 4 x 16-lane groups, 8 gathers in flight.
// y is nt-major permuted: y'[r][li*8+m] = C[r][m*16+li] -> lane li's a_m is
// out column li+16m. out currently holds the PERMUTED f32 self+bias (written
// by k_gemm_rank); load it early (latency hidden under the gather loop),
// add, and write the row back unpermuted.
__global__ __launch_bounds__(256) void k_agg(
    const unsigned short* __restrict__ y, const uint2* __restrict__ sorted,
    const int* __restrict__ ofs, const int* __restrict__ bsum,
    const int* __restrict__ cnt, int N,
    float* __restrict__ out) {
    int w = threadIdx.x >> 6, l = threadIdx.x & 63;
    int node = blockIdx.x * 4 + w;
    if (node >= N) return;
    int s = ofs[node] + bsum[node >> 10], n = cnt[node];
    int g = l >> 4, li = l & 15;
    float4 s0, s1;
    if (l < 16) {   // early self-load (permuted): self for cols li+16m
        const float4* spf = (const float4*)(out + (size_t)node * D + li * 8);
        s0 = spf[0]; s1 = spf[1];
    }
    const uint2* sp = sorted + s;
    float a0 = 0.f, a1 = 0.f, a2 = 0.f, a3 = 0.f;
    float a4 = 0.f, a5 = 0.f, a6 = 0.f, a7 = 0.f;
    int j = g;
    for (; j + 4 < n; j += 8) {
        uint2 pa = sp[j];
        uint2 pb = sp[j + 4];
        uint4 va = *(const uint4*)(y + (size_t)pa.x * D + li * 8);
        uint4 vb = *(const uint4*)(y + (size_t)pb.x * D + li * 8);
        float wa = __uint_as_float(pa.y), wb = __uint_as_float(pb.y);
        a0 += wa * bf2f(va.x & 0xFFFFu); a1 += wa * bf2f(va.x >> 16);
        a2 += wa * bf2f(va.y & 0xFFFFu); a3 += wa * bf2f(va.y >> 16);
        a4 += wa * bf2f(va.z & 0xFFFFu); a5 += wa * bf2f(va.z >> 16);
        a6 += wa * bf2f(va.w & 0xFFFFu); a7 += wa * bf2f(va.w >> 16);
        a0 += wb * bf2f(vb.x & 0xFFFFu); a1 += wb * bf2f(vb.x >> 16);
        a2 += wb * bf2f(vb.y & 0xFFFFu); a3 += wb * bf2f(vb.y >> 16);
        a4 += wb * bf2f(vb.z & 0xFFFFu); a5 += wb * bf2f(vb.z >> 16);
        a6 += wb * bf2f(vb.w & 0xFFFFu); a7 += wb * bf2f(vb.w >> 16);
    }
    if (j < n) {
        uint2 p = sp[j];
        uint4 v = *(const uint4*)(y + (size_t)p.x * D + li * 8);
        float wt = __uint_as_float(p.y);
        a0 += wt * bf2f(v.x & 0xFFFFu); a1 += wt * bf2f(v.x >> 16);
        a2 += wt * bf2f(v.y & 0xFFFFu); a3 += wt * bf2f(v.y >> 16);
        a4 += wt * bf2f(v.z & 0xFFFFu); a5 += wt * bf2f(v.z >> 16);
        a6 += wt * bf2f(v.w & 0xFFFFu); a7 += wt * bf2f(v.w >> 16);
    }
    // butterfly across the 4 groups (xor 16, then xor 32): all lanes -> full sums
    a0 += __shfl_xor(a0, 16, 64); a1 += __shfl_xor(a1, 16, 64);
    a2 += __shfl_xor(a2, 16, 64); a3 += __shfl_xor(a3, 16, 64);
    a4 += __shfl_xor(a4, 16, 64); a5 += __shfl_xor(a5, 16, 64);
    a6 += __shfl_xor(a6, 16, 64); a7 += __shfl_xor(a7, 16, 64);
    a0 += __shfl_xor(a0, 32, 64); a1 += __shfl_xor(a1, 32, 64);
    a2 += __shfl_xor(a2, 32, 64); a3 += __shfl_xor(a3, 32, 64);
    a4 += __shfl_xor(a4, 32, 64); a5 += __shfl_xor(a5, 32, 64);
    a6 += __shfl_xor(a6, 32, 64); a7 += __shfl_xor(a7, 32, 64);
    if (l < 16) {   // lane li owns cols li+16m; each m-group is one 64-B line
        float* op = out + (size_t)node * D + li;
        op[0]   = a0 + s0.x; op[16]  = a1 + s0.y;
        op[32]  = a2 + s0.z; op[48]  = a3 + s0.w;
        op[64]  = a4 + s1.x; op[80]  = a5 + s1.y;
        op[96]  = a6 + s1.z; op[112] = a7 + s1.w;
    }
}

extern "C" void kernel_launch(void* const* d_in, const int* in_sizes, int n_in,
                              void* d_out, int out_size, void* d_ws, size_t ws_size,
                              hipStream_t stream) {
    const float* x    = (const float*)d_in[0];
    const int*   esrc = (const int*)d_in[1];
    const int*   edst = (const int*)d_in[2];
    const float* ew   = (const float*)d_in[3];
    const float* Wn   = (const float*)d_in[4];
    const float* Wsf  = (const float*)d_in[5];
    const float* bias = (const float*)d_in[6];
    float* out = (float*)d_out;
    int N = in_sizes[0] / D;
    int E = in_sizes[1];

    char* ws = (char*)d_ws;
    size_t off = 0;
    unsigned short* WTs = (unsigned short*)(ws + off); off += 256 * 128 * sizeof(unsigned short);
    unsigned short* yb  = (unsigned short*)(ws + off); off += (size_t)N * D * sizeof(unsigned short);
    off = (off + 255) & ~(size_t)255;
    int* cnt  = (int*)(ws + off); off += (size_t)N * 4; off = (off + 255) & ~(size_t)255;
    int* ofs  = (int*)(ws + off); off += (size_t)N * 4; off = (off + 255) & ~(size_t)255;
    int* bsum = (int*)(ws + off); off += 1024;
    int* rank = (int*)(ws + off); off += (size_t)E * 4; off = (off + 255) & ~(size_t)255;
    uint2* sorted = (uint2*)(ws + off); off += (size_t)E * 8;

    k_build_wt<<<128, 256, 0, stream>>>(Wn, Wsf, WTs, cnt, N);

    int GB = (N + 127) / 128;                 // 782
    int RB = (E + 1023) / 1024;               // 1563
    int RBH = (RB + 1) / 2;                   // 782
    int M = (GB > RBH ? GB : RBH);
    k_gemm_rank<<<M * 3, 256, 0, stream>>>(x, WTs, bias, N, yb, out,
                                           edst, E, cnt, rank);

    int NB = (N + 1023) / 1024;
    k_scanA<<<NB, 1024, 0, stream>>>(cnt, N, ofs, bsum);
    k_scanB<<<1, 128, 0, stream>>>(bsum, NB);
    k_fill<<<(E + 1023) / 1024, 256, 0, stream>>>(esrc, edst, ew, rank, E, ofs, bsum, sorted);

    k_agg<<<(N + 3) / 4, 256, 0, stream>>>(yb, sorted, ofs, bsum, cnt, N, out);
}

// Round 7
// 296.639 us; speedup vs baseline: 1.1866x; 1.0134x over previous
//
#include <hip/hip_runtime.h>
#include <hip/hip_bf16.h>

#define D 128

typedef __bf16 bf16x8 __attribute__((ext_vector_type(8)));
typedef unsigned short u16x8 __attribute__((ext_vector_type(8)));
typedef float f32x4 __attribute__((ext_vector_type(4)));

__device__ __forceinline__ unsigned short f2bf(float f) {
    unsigned u = __float_as_uint(f);
    u += 0x7FFFu + ((u >> 16) & 1u);
    return (unsigned short)(u >> 16);
}
__device__ __forceinline__ float bf2f(unsigned u16) {
    return __uint_as_float(u16 << 16);
}

// Build W = [W_nbrs | W_self]^T as bf16, XOR-swizzled so the GEMMs can stage it
// linearly into LDS and read B fragments conflict-free.
// Element (k, c) -> WTs[c*128 + (((k>>3) ^ (c&15)) << 3) + (k&7)]
// Also zeroes cnt[] (replaces a separate memset dispatch).
__global__ void k_build_wt(const float* __restrict__ Wn, const float* __restrict__ Ws,
                           unsigned short* __restrict__ WTs,
                           int* __restrict__ cnt, int N) {
    int g = blockIdx.x * blockDim.x + threadIdx.x;   // 0..32767
    int k = g >> 8;          // 0..127
    int c = g & 255;         // 0..255 (coalesced reads along c)
    float v = (c < 128) ? Wn[k * 128 + c] : Ws[k * 128 + (c - 128)];
    int chunk = k >> 3;
    WTs[c * 128 + (((chunk ^ (c & 15)) << 3) | (k & 7))] = f2bf(v);
    for (int i = g; i < N; i += 32768) cnt[i] = 0;
}

// k1: even blocks = gemm_y (64 rows, phase-0 only: y' = bf16(x@W_nbrs), nt-major
// permuted, one barrier); odd blocks = rank (1024 edges, int4 loads, 4 atomic
// chains in flight, vector rank store).
__global__ __launch_bounds__(256) void k1_gemm_y_rank(
    const float* __restrict__ x, const unsigned short* __restrict__ WTs, int N,
    unsigned short* __restrict__ y,
    const int* __restrict__ edst, int E,
    int* __restrict__ cnt, int* __restrict__ rank) {
    __shared__ unsigned short sm[128 * 128];   // 32 KB (B0 half)
    int b = blockIdx.x;
    int tid = threadIdx.x;
    if (b & 1) {
        // ---- rank path ----
        int e0 = (b >> 1) * 1024 + tid * 4;
        if (e0 + 3 < E) {
            int4 d4 = *(const int4*)(edst + e0);
            int r0 = atomicAdd(&cnt[d4.x], 1);
            int r1 = atomicAdd(&cnt[d4.y], 1);
            int r2 = atomicAdd(&cnt[d4.z], 1);
            int r3 = atomicAdd(&cnt[d4.w], 1);
            *(int4*)(rank + e0) = make_int4(r0, r1, r2, r3);
        } else {
            for (int e = e0; e < E && e < e0 + 4; ++e)
                rank[e] = atomicAdd(&cnt[edst[e]], 1);
        }
        return;
    }
    // ---- gemm_y path ----
    int gb = b >> 1;
    int brow = gb * 64;
    if (brow >= N) return;                   // block-uniform
    int w = tid >> 6, l = tid & 63;
    int row0 = brow + w * 16;
    int c15 = l & 15;
    int kgrp = l >> 4;                       // 0..3
    const uint4* gs = (const uint4*)WTs;
    uint4* ss = (uint4*)sm;
    uint4 st[8];
    #pragma unroll
    for (int r = 0; r < 8; ++r) st[r] = gs[r * 256 + tid];      // B0 half
    int arow = row0 + c15;                   // A: row = lane%16
    bool avalid = (arow < N);
    const float* xr = x + (size_t)arow * D;
    bf16x8 afrag[4];
    #pragma unroll
    for (int ks = 0; ks < 4; ++ks) {
        int k0 = ks * 32 + kgrp * 8;         // A: k = 8*(lane/16) + j
        float4 a0, a1;
        if (avalid) { a0 = *(const float4*)(xr + k0); a1 = *(const float4*)(xr + k0 + 4); }
        else { a0 = make_float4(0.f, 0.f, 0.f, 0.f); a1 = a0; }
        bf16x8 f;
        f[0] = (__bf16)a0.x; f[1] = (__bf16)a0.y; f[2] = (__bf16)a0.z; f[3] = (__bf16)a0.w;
        f[4] = (__bf16)a1.x; f[5] = (__bf16)a1.y; f[6] = (__bf16)a1.z; f[7] = (__bf16)a1.w;
        afrag[ks] = f;
    }
    #pragma unroll
    for (int r = 0; r < 8; ++r) ss[r * 256 + tid] = st[r];
    __syncthreads();
    f32x4 acc[8];
    #pragma unroll
    for (int nt = 0; nt < 8; ++nt) {
        int c = nt * 16 + c15;
        f32x4 a = {0.f, 0.f, 0.f, 0.f};
        #pragma unroll
        for (int ks = 0; ks < 4; ++ks) {
            int chunk = ks * 4 + kgrp;
            const bf16x8* bp = (const bf16x8*)(sm + c * 128 + ((chunk ^ c15) << 3));
            a = __builtin_amdgcn_mfma_f32_16x16x32_bf16(afrag[ks], *bp, a, 0, 0, 0);
        }
        acc[nt] = a;
    }
    int orow = row0 + kgrp * 4;              // C/D: row = 4*(lane/16) + j
    #pragma unroll
    for (int j = 0; j < 4; ++j) {            // permuted 16-B stores
        int r = orow + j;
        if (r < N) {
            u16x8 f;
            #pragma unroll
            for (int nt = 0; nt < 8; ++nt) f[nt] = f2bf(acc[nt][j]);
            *(u16x8*)(y + (size_t)r * D + c15 * 8) = f;
        }
    }
}

__global__ void k_scanA(const int* __restrict__ cnt, int N,
                        int* __restrict__ ofs, int* __restrict__ bsum) {
    __shared__ int lds[1024];
    int t = threadIdx.x, i = blockIdx.x * 1024 + t;
    int v = (i < N) ? cnt[i] : 0;
    lds[t] = v; __syncthreads();
    for (int d = 1; d < 1024; d <<= 1) {
        int x = (t >= d) ? lds[t - d] : 0; __syncthreads();
        lds[t] += x; __syncthreads();
    }
    if (i < N) ofs[i] = lds[t] - v;           // local exclusive scan
    if (t == 1023) bsum[blockIdx.x] = lds[t]; // block total
}

__global__ void k_scanB(int* __restrict__ bsum, int NB) {   // NB <= 128
    __shared__ int lds[128];
    int t = threadIdx.x;
    int v = (t < NB) ? bsum[t] : 0;
    lds[t] = v; __syncthreads();
    for (int d = 1; d < 128; d <<= 1) {
        int x = (t >= d) ? lds[t - d] : 0; __syncthreads();
        lds[t] += x; __syncthreads();
    }
    if (t < NB) bsum[t] = lds[t] - v;         // exclusive block bases
}

// k2: even blocks = gemm_self (x@W_self + bias, f32, nt-major permuted,
// straight into d_out; x/WTs are L3/L2-resident by now); odd blocks = fill
// (no atomics: pos = ofs[d] + bsum[d>>10] + rank[e]; uint2 scatter).
__global__ __launch_bounds__(256) void k2_gemm_self_fill(
    const float* __restrict__ x, const unsigned short* __restrict__ WTs,
    const float* __restrict__ bias, int N,
    float* __restrict__ out,
    const int* __restrict__ src, const int* __restrict__ dst,
    const float* __restrict__ ew, const int* __restrict__ rank, int E,
    const int* __restrict__ ofs, const int* __restrict__ bsum,
    uint2* __restrict__ sorted) {
    __shared__ unsigned short sm[128 * 128];   // 32 KB (B1 half)
    int b = blockIdx.x;
    int tid = threadIdx.x;
    if (b & 1) {
        // ---- fill path ----
        int e0 = (b >> 1) * 1024 + tid * 4;
        if (e0 + 3 < E) {
            int4 d4 = *(const int4*)(dst + e0);
            int4 s4 = *(const int4*)(src + e0);
            float4 w4 = *(const float4*)(ew + e0);
            int4 r4 = *(const int4*)(rank + e0);
            sorted[ofs[d4.x] + bsum[d4.x >> 10] + r4.x] = make_uint2((unsigned)s4.x, __float_as_uint(w4.x));
            sorted[ofs[d4.y] + bsum[d4.y >> 10] + r4.y] = make_uint2((unsigned)s4.y, __float_as_uint(w4.y));
            sorted[ofs[d4.z] + bsum[d4.z >> 10] + r4.z] = make_uint2((unsigned)s4.z, __float_as_uint(w4.z));
            sorted[ofs[d4.w] + bsum[d4.w >> 10] + r4.w] = make_uint2((unsigned)s4.w, __float_as_uint(w4.w));
        } else {
            for (int e = e0; e < E && e < e0 + 4; ++e) {
                int d = dst[e];
                sorted[ofs[d] + bsum[d >> 10] + rank[e]] =
                    make_uint2((unsigned)src[e], __float_as_uint(ew[e]));
            }
        }
        return;
    }
    // ---- gemm_self path ----
    int gb = b >> 1;
    int brow = gb * 64;
    if (brow >= N) return;
    int w = tid >> 6, l = tid & 63;
    int row0 = brow + w * 16;
    int c15 = l & 15;
    int kgrp = l >> 4;
    const uint4* gs = (const uint4*)WTs;
    uint4* ss = (uint4*)sm;
    uint4 st[8];
    #pragma unroll
    for (int r = 0; r < 8; ++r) st[r] = gs[2048 + r * 256 + tid];   // B1 half
    int arow = row0 + c15;
    bool avalid = (arow < N);
    const float* xr = x + (size_t)arow * D;
    bf16x8 afrag[4];
    #pragma unroll
    for (int ks = 0; ks < 4; ++ks) {
        int k0 = ks * 32 + kgrp * 8;
        float4 a0, a1;
        if (avalid) { a0 = *(const float4*)(xr + k0); a1 = *(const float4*)(xr + k0 + 4); }
        else { a0 = make_float4(0.f, 0.f, 0.f, 0.f); a1 = a0; }
        bf16x8 f;
        f[0] = (__bf16)a0.x; f[1] = (__bf16)a0.y; f[2] = (__bf16)a0.z; f[3] = (__bf16)a0.w;
        f[4] = (__bf16)a1.x; f[5] = (__bf16)a1.y; f[6] = (__bf16)a1.z; f[7] = (__bf16)a1.w;
        afrag[ks] = f;
    }
    #pragma unroll
    for (int r = 0; r < 8; ++r) ss[r * 256 + tid] = st[r];
    __syncthreads();
    f32x4 acc[8];
    #pragma unroll
    for (int nt = 0; nt < 8; ++nt) {
        int c = nt * 16 + c15;
        f32x4 a = {0.f, 0.f, 0.f, 0.f};
        #pragma unroll
        for (int ks = 0; ks < 4; ++ks) {
            int chunk = ks * 4 + kgrp;
            const bf16x8* bp = (const bf16x8*)(sm + c * 128 + ((chunk ^ c15) << 3));
            a = __builtin_amdgcn_mfma_f32_16x16x32_bf16(afrag[ks], *bp, a, 0, 0, 0);
        }
        acc[nt] = a;
    }
    float bv[8];
    #pragma unroll
    for (int nt = 0; nt < 8; ++nt) bv[nt] = bias[nt * 16 + c15];
    int orow = row0 + kgrp * 4;
    #pragma unroll
    for (int j = 0; j < 4; ++j) {            // permuted f32 store; k_agg unpermutes
        int r = orow + j;
        if (r < N) {
            float4 s0 = make_float4(acc[0][j] + bv[0], acc[1][j] + bv[1],
                                    acc[2][j] + bv[2], acc[3][j] + bv[3]);
            float4 s1 = make_float4(acc[4][j] + bv[4], acc[5][j] + bv[5],
                                    acc[6][j] + bv[6], acc[7][j] + bv[7]);
            float4* op = (float4*)(out + (size_t)r * D + c15 * 8);
            op[0] = s0; op[1] = s1;
        }
    }
}

// One wave per destination node, 4 x 16-lane groups, 8 gathers in flight.
// y is nt-major permuted: y'[r][li*8+m] = C[r][m*16+li] -> lane li's a_m is
// out column li+16m. out holds the PERMUTED f32 self+bias (from k2); load it
// early (hidden under the gather loop), add, write the row back unpermuted.
__global__ __launch_bounds__(256) void k_agg(
    const unsigned short* __restrict__ y, const uint2* __restrict__ sorted,
    const int* __restrict__ ofs, const int* __restrict__ bsum,
    const int* __restrict__ cnt, int N,
    float* __restrict__ out) {
    int w = threadIdx.x >> 6, l = threadIdx.x & 63;
    int node = blockIdx.x * 4 + w;
    if (node >= N) return;
    int s = ofs[node] + bsum[node >> 10], n = cnt[node];
    int g = l >> 4, li = l & 15;
    float4 s0, s1;
    if (l < 16) {   // early self-load (permuted)
        const float4* spf = (const float4*)(out + (size_t)node * D + li * 8);
        s0 = spf[0]; s1 = spf[1];
    }
    const uint2* sp = sorted + s;
    float a0 = 0.f, a1 = 0.f, a2 = 0.f, a3 = 0.f;
    float a4 = 0.f, a5 = 0.f, a6 = 0.f, a7 = 0.f;
    int j = g;
    for (; j + 4 < n; j += 8) {
        uint2 pa = sp[j];
        uint2 pb = sp[j + 4];
        uint4 va = *(const uint4*)(y + (size_t)pa.x * D + li * 8);
        uint4 vb = *(const uint4*)(y + (size_t)pb.x * D + li * 8);
        float wa = __uint_as_float(pa.y), wb = __uint_as_float(pb.y);
        a0 += wa * bf2f(va.x & 0xFFFFu); a1 += wa * bf2f(va.x >> 16);
        a2 += wa * bf2f(va.y & 0xFFFFu); a3 += wa * bf2f(va.y >> 16);
        a4 += wa * bf2f(va.z & 0xFFFFu); a5 += wa * bf2f(va.z >> 16);
        a6 += wa * bf2f(va.w & 0xFFFFu); a7 += wa * bf2f(va.w >> 16);
        a0 += wb * bf2f(vb.x & 0xFFFFu); a1 += wb * bf2f(vb.x >> 16);
        a2 += wb * bf2f(vb.y & 0xFFFFu); a3 += wb * bf2f(vb.y >> 16);
        a4 += wb * bf2f(vb.z & 0xFFFFu); a5 += wb * bf2f(vb.z >> 16);
        a6 += wb * bf2f(vb.w & 0xFFFFu); a7 += wb * bf2f(vb.w >> 16);
    }
    if (j < n) {
        uint2 p = sp[j];
        uint4 v = *(const uint4*)(y + (size_t)p.x * D + li * 8);
        float wt = __uint_as_float(p.y);
        a0 += wt * bf2f(v.x & 0xFFFFu); a1 += wt * bf2f(v.x >> 16);
        a2 += wt * bf2f(v.y & 0xFFFFu); a3 += wt * bf2f(v.y >> 16);
        a4 += wt * bf2f(v.z & 0xFFFFu); a5 += wt * bf2f(v.z >> 16);
        a6 += wt * bf2f(v.w & 0xFFFFu); a7 += wt * bf2f(v.w >> 16);
    }
    a0 += __shfl_xor(a0, 16, 64); a1 += __shfl_xor(a1, 16, 64);
    a2 += __shfl_xor(a2, 16, 64); a3 += __shfl_xor(a3, 16, 64);
    a4 += __shfl_xor(a4, 16, 64); a5 += __shfl_xor(a5, 16, 64);
    a6 += __shfl_xor(a6, 16, 64); a7 += __shfl_xor(a7, 16, 64);
    a0 += __shfl_xor(a0, 32, 64); a1 += __shfl_xor(a1, 32, 64);
    a2 += __shfl_xor(a2, 32, 64); a3 += __shfl_xor(a3, 32, 64);
    a4 += __shfl_xor(a4, 32, 64); a5 += __shfl_xor(a5, 32, 64);
    a6 += __shfl_xor(a6, 32, 64); a7 += __shfl_xor(a7, 32, 64);
    if (l < 16) {   // lane li owns cols li+16m; each m-group is one 64-B line
        float* op = out + (size_t)node * D + li;
        op[0]   = a0 + s0.x; op[16]  = a1 + s0.y;
        op[32]  = a2 + s0.z; op[48]  = a3 + s0.w;
        op[64]  = a4 + s1.x; op[80]  = a5 + s1.y;
        op[96]  = a6 + s1.z; op[112] = a7 + s1.w;
    }
}

extern "C" void kernel_launch(void* const* d_in, const int* in_sizes, int n_in,
                              void* d_out, int out_size, void* d_ws, size_t ws_size,
                              hipStream_t stream) {
    const float* x    = (const float*)d_in[0];
    const int*   esrc = (const int*)d_in[1];
    const int*   edst = (const int*)d_in[2];
    const float* ew   = (const float*)d_in[3];
    const float* Wn   = (const float*)d_in[4];
    const float* Wsf  = (const float*)d_in[5];
    const float* bias = (const float*)d_in[6];
    float* out = (float*)d_out;
    int N = in_sizes[0] / D;
    int E = in_sizes[1];

    char* ws = (char*)d_ws;
    size_t off = 0;
    unsigned short* WTs = (unsigned short*)(ws + off); off += 256 * 128 * sizeof(unsigned short);
    unsigned short* yb  = (unsigned short*)(ws + off); off += (size_t)N * D * sizeof(unsigned short);
    off = (off + 255) & ~(size_t)255;
    int* cnt  = (int*)(ws + off); off += (size_t)N * 4; off = (off + 255) & ~(size_t)255;
    int* ofs  = (int*)(ws + off); off += (size_t)N * 4; off = (off + 255) & ~(size_t)255;
    int* bsum = (int*)(ws + off); off += 1024;
    int* rank = (int*)(ws + off); off += (size_t)E * 4; off = (off + 255) & ~(size_t)255;
    uint2* sorted = (uint2*)(ws + off); off += (size_t)E * 8;

    k_build_wt<<<128, 256, 0, stream>>>(Wn, Wsf, WTs, cnt, N);

    int GB = (N + 63) / 64;                   // 1563
    int RB = (E + 1023) / 1024;               // 1563
    int M1 = (GB > RB ? GB : RB);
    k1_gemm_y_rank<<<M1 * 2, 256, 0, stream>>>(x, WTs, N, yb, edst, E, cnt, rank);

    int NB = (N + 1023) / 1024;
    k_scanA<<<NB, 1024, 0, stream>>>(cnt, N, ofs, bsum);
    k_scanB<<<1, 128, 0, stream>>>(bsum, NB);

    k2_gemm_self_fill<<<M1 * 2, 256, 0, stream>>>(x, WTs, bias, N, out,
                                                  esrc, edst, ew, rank, E,
                                                  ofs, bsum, sorted);

    k_agg<<<(N + 3) / 4, 256, 0, stream>>>(yb, sorted, ofs, bsum, cnt, N, out);
}